// Round 1
// baseline (69.034 us; speedup 1.0000x reference)
//
#include <hip/hip_runtime.h>
#include <math.h>

#define B_ 32
#define L_ 2048
#define D_ 1024
#define C_ 1024
#define CSPLIT 16
#define NSPLIT 32
#define CHUNK (L_ / NSPLIT)   // 64

// ws layout (floats):
//   v     : [B_, D_]            off 0        (32768)
//   cb    : [B_]                off 32768    (32)
//   energ : [B_, L_]            off 32800    (65536)
//   vpart : [CSPLIT, B_, D_]    off 98336    (524288)
//   cpart : [B_, NSPLIT, D_]    off 622624   (1048576)
// total ~6.7 MB

// ---- K1a: partial v[b,d] = sum_{c in chunk} query[b,c] * W_h[c,d] ----
__global__ void k_vpart(const float* __restrict__ q, const float* __restrict__ W,
                        float* __restrict__ vpart) {
    int b  = blockIdx.y;
    int cc = blockIdx.x;            // c-chunk of 64
    int t  = threadIdx.x;           // 256 threads, thread owns d = 4t..4t+3
    const float* qb = q + b * C_;
    float ax = 0.f, ay = 0.f, az = 0.f, aw = 0.f;
    for (int i = 0; i < C_ / CSPLIT; ++i) {
        int c = cc * (C_ / CSPLIT) + i;
        float qv = qb[c];
        float4 w = *reinterpret_cast<const float4*>(W + (size_t)c * D_ + t * 4);
        ax = fmaf(qv, w.x, ax); ay = fmaf(qv, w.y, ay);
        az = fmaf(qv, w.z, az); aw = fmaf(qv, w.w, aw);
    }
    float4 o = {ax, ay, az, aw};
    *reinterpret_cast<float4*>(vpart + ((size_t)cc * B_ + b) * D_ + t * 4) = o;
}

// ---- K1b: reduce vpart -> v;  cb[b] = dot(b_h, query[b]) ----
__global__ void k_vreduce(const float* __restrict__ vpart, float* __restrict__ v,
                          const float* __restrict__ q, const float* __restrict__ bh,
                          float* __restrict__ cb) {
    int b = blockIdx.x, t = threadIdx.x;
    float ax = 0.f, ay = 0.f, az = 0.f, aw = 0.f;
    for (int cc = 0; cc < CSPLIT; ++cc) {
        float4 p = *reinterpret_cast<const float4*>(vpart + ((size_t)cc * B_ + b) * D_ + t * 4);
        ax += p.x; ay += p.y; az += p.z; aw += p.w;
    }
    float4 o = {ax, ay, az, aw};
    *reinterpret_cast<float4*>(v + (size_t)b * D_ + t * 4) = o;

    float s = 0.f;
    for (int c = t; c < C_; c += 256) s += bh[c] * q[b * C_ + c];
    __shared__ float red[256];
    red[t] = s; __syncthreads();
    for (int off = 128; off > 0; off >>= 1) {
        if (t < off) red[t] += red[t + off];
        __syncthreads();
    }
    if (t == 0) cb[b] = red[0];
}

// ---- K2: energies[b,l] = seq[b,l,:].v[b,:] + cb[b], only l < len[b] ----
__global__ void k_energy(const float* __restrict__ seq, const float* __restrict__ v,
                         const float* __restrict__ cb, const int* __restrict__ lenp,
                         float* __restrict__ energ) {
    int blk  = blockIdx.x;                       // B_ * L_/4 blocks
    int b    = blk >> 9;                         // L_/4 = 512
    int l    = ((blk & 511) << 2) + (threadIdx.x >> 6);
    int lane = threadIdx.x & 63;
    if (l >= lenp[b]) return;                    // masked: never read downstream
    const float* row = seq + ((size_t)b * L_ + l) * D_;
    const float* vb  = v + (size_t)b * D_;
    float acc = 0.f;
    #pragma unroll
    for (int it = 0; it < 4; ++it) {
        int d = it * 256 + lane * 4;
        float4 s4 = *reinterpret_cast<const float4*>(row + d);
        float4 v4 = *reinterpret_cast<const float4*>(vb + d);
        acc = fmaf(s4.x, v4.x, acc); acc = fmaf(s4.y, v4.y, acc);
        acc = fmaf(s4.z, v4.z, acc); acc = fmaf(s4.w, v4.w, acc);
    }
    #pragma unroll
    for (int off = 32; off > 0; off >>= 1) acc += __shfl_xor(acc, off);
    if (lane == 0) energ[b * L_ + l] = acc + cb[b];
}

// ---- K3: masked softmax per b row; scores[l>=len] = 0 exactly ----
__global__ void k_softmax(const float* __restrict__ energ, const int* __restrict__ lenp,
                          float* __restrict__ scores) {
    int b = blockIdx.x, t = threadIdx.x;         // 256 threads
    int len = lenp[b];
    const float* e = energ + (size_t)b * L_;
    float vals[8];
    float m = -INFINITY;
    #pragma unroll
    for (int i = 0; i < 8; ++i) {
        int l = t + i * 256;
        vals[i] = (l < len) ? e[l] : -INFINITY;
        m = fmaxf(m, vals[i]);
    }
    __shared__ float red[256];
    red[t] = m; __syncthreads();
    for (int off = 128; off > 0; off >>= 1) {
        if (t < off) red[t] = fmaxf(red[t], red[t + off]);
        __syncthreads();
    }
    m = red[0]; __syncthreads();
    float s = 0.f;
    #pragma unroll
    for (int i = 0; i < 8; ++i) {
        int l = t + i * 256;
        float p = (l < len) ? expf(vals[i] - m) : 0.f;
        vals[i] = p; s += p;
    }
    red[t] = s; __syncthreads();
    for (int off = 128; off > 0; off >>= 1) {
        if (t < off) red[t] += red[t + off];
        __syncthreads();
    }
    float inv = 1.f / red[0];
    #pragma unroll
    for (int i = 0; i < 8; ++i) {
        int l = t + i * 256;
        scores[(size_t)b * L_ + l] = vals[i] * inv;   // masked: 0
    }
}

// ---- K4: partial contexts over L-chunks (skip fully-masked chunks) ----
__global__ void k_cpart(const float* __restrict__ seq, const float* __restrict__ scores,
                        const int* __restrict__ lenp, float* __restrict__ cpart) {
    int b  = blockIdx.y;
    int sp = blockIdx.x;             // 0..NSPLIT-1
    int t  = threadIdx.x;            // 256, owns d = 4t..4t+3
    int len = lenp[b];
    int l0 = sp * CHUNK;
    if (l0 >= len) return;           // cpart never read for these
    int l1 = min(l0 + CHUNK, len);
    const float* sc = scores + (size_t)b * L_;
    float ax = 0.f, ay = 0.f, az = 0.f, aw = 0.f;
    for (int l = l0; l < l1; ++l) {
        float w = sc[l];
        float4 s4 = *reinterpret_cast<const float4*>(seq + ((size_t)b * L_ + l) * D_ + t * 4);
        ax = fmaf(w, s4.x, ax); ay = fmaf(w, s4.y, ay);
        az = fmaf(w, s4.z, az); aw = fmaf(w, s4.w, aw);
    }
    float4 o = {ax, ay, az, aw};
    *reinterpret_cast<float4*>(cpart + ((size_t)b * NSPLIT + sp) * D_ + t * 4) = o;
}

// ---- K5: reduce valid partials -> contexts ----
__global__ void k_creduce(const float* __restrict__ cpart, const int* __restrict__ lenp,
                          float* __restrict__ ctx) {
    int b = blockIdx.x, t = threadIdx.x;
    int len = lenp[b];
    int nsp = (len + CHUNK - 1) / CHUNK;
    float ax = 0.f, ay = 0.f, az = 0.f, aw = 0.f;
    for (int sp = 0; sp < nsp; ++sp) {
        float4 p = *reinterpret_cast<const float4*>(cpart + ((size_t)b * NSPLIT + sp) * D_ + t * 4);
        ax += p.x; ay += p.y; az += p.z; aw += p.w;
    }
    float4 o = {ax, ay, az, aw};
    *reinterpret_cast<float4*>(ctx + (size_t)b * D_ + t * 4) = o;
}

extern "C" void kernel_launch(void* const* d_in, const int* in_sizes, int n_in,
                              void* d_out, int out_size, void* d_ws, size_t ws_size,
                              hipStream_t stream) {
    const float* seq     = (const float*)d_in[0];   // [B,L,D]
    const float* query   = (const float*)d_in[1];   // [B,C]
    const int*   lengths = (const int*)  d_in[2];   // [B]
    const float* W_h     = (const float*)d_in[3];   // [C,D]
    const float* b_h     = (const float*)d_in[4];   // [C]

    float* out    = (float*)d_out;
    float* ctx    = out;                 // [B,D]
    float* scores = out + B_ * D_;       // [B,L]

    float* ws    = (float*)d_ws;
    float* v     = ws;                   // 32768
    float* cb    = ws + 32768;           // 32
    float* energ = ws + 32800;           // 65536
    float* vpart = ws + 98336;           // 524288
    float* cpart = ws + 98336 + CSPLIT * B_ * D_;   // 1048576

    k_vpart  <<<dim3(CSPLIT, B_), 256, 0, stream>>>(query, W_h, vpart);
    k_vreduce<<<B_, 256, 0, stream>>>(vpart, v, query, b_h, cb);
    k_energy <<<B_ * (L_ / 4), 256, 0, stream>>>(seq, v, cb, lengths, energ);
    k_softmax<<<B_, 256, 0, stream>>>(energ, lengths, scores);
    k_cpart  <<<dim3(NSPLIT, B_), 256, 0, stream>>>(seq, scores, lengths, cpart);
    k_creduce<<<B_, 256, 0, stream>>>(cpart, lengths, ctx);
}

// Round 2
// 49.067 us; speedup vs baseline: 1.4069x; 1.4069x over previous
//
#include <hip/hip_runtime.h>
#include <math.h>

#define B_ 32
#define L_ 2048
#define D_ 1024
#define C_ 1024
#define CSPLIT 16
#define WROWS 8            // rows per wave in fused kernel
#define BROWS 32           // rows per block (4 waves)
#define NCH (L_ / BROWS)   // 64 chunks per batch row

// ws layout (floats):
//   v     : [B_, D_]          off 0
//   cb    : [B_]              off 32768
//   energ : [B_, L_]          off 32800
//   vpart : [CSPLIT, B_, D_]  off 98336
//   pm    : [B_, NCH]         off 622624
//   ps    : [B_, NCH]         off 624672
//   pc    : [B_, NCH, D_]     off 626720   (8 MB)

// ---- K1a: partial v[b,d] = sum_{c in chunk} query[b,c] * W_h[c,d] ----
__global__ __launch_bounds__(256) void k_vpart(const float* __restrict__ q,
                                               const float* __restrict__ W,
                                               float* __restrict__ vpart) {
    int b  = blockIdx.y;
    int cc = blockIdx.x;
    int t  = threadIdx.x;
    const float* qb = q + b * C_;
    float ax = 0.f, ay = 0.f, az = 0.f, aw = 0.f;
    for (int i = 0; i < C_ / CSPLIT; ++i) {
        int c = cc * (C_ / CSPLIT) + i;
        float qv = qb[c];
        float4 w = *reinterpret_cast<const float4*>(W + (size_t)c * D_ + t * 4);
        ax = fmaf(qv, w.x, ax); ay = fmaf(qv, w.y, ay);
        az = fmaf(qv, w.z, az); aw = fmaf(qv, w.w, aw);
    }
    float4 o = {ax, ay, az, aw};
    *reinterpret_cast<float4*>(vpart + ((size_t)cc * B_ + b) * D_ + t * 4) = o;
}

// ---- K1b: reduce vpart -> v;  cb[b] = dot(b_h, query[b]) ----
__global__ __launch_bounds__(256) void k_vreduce(const float* __restrict__ vpart,
                                                 float* __restrict__ v,
                                                 const float* __restrict__ q,
                                                 const float* __restrict__ bh,
                                                 float* __restrict__ cb) {
    int b = blockIdx.x, t = threadIdx.x;
    float ax = 0.f, ay = 0.f, az = 0.f, aw = 0.f;
    for (int cc = 0; cc < CSPLIT; ++cc) {
        float4 p = *reinterpret_cast<const float4*>(vpart + ((size_t)cc * B_ + b) * D_ + t * 4);
        ax += p.x; ay += p.y; az += p.z; aw += p.w;
    }
    float4 o = {ax, ay, az, aw};
    *reinterpret_cast<float4*>(v + (size_t)b * D_ + t * 4) = o;

    float s = 0.f;
    for (int c = t; c < C_; c += 256) s += bh[c] * q[b * C_ + c];
    __shared__ float red[256];
    red[t] = s; __syncthreads();
    for (int off = 128; off > 0; off >>= 1) {
        if (t < off) red[t] += red[t + off];
        __syncthreads();
    }
    if (t == 0) cb[b] = red[0];
}

// ---- K2 fused: energies + online-softmax context partials, ONE seq pass ----
__global__ __launch_bounds__(256) void k_fused(const float* __restrict__ seq,
                                               const float* __restrict__ v,
                                               const float* __restrict__ cb,
                                               const int* __restrict__ lenp,
                                               float* __restrict__ energ,
                                               float* __restrict__ pm,
                                               float* __restrict__ ps,
                                               float* __restrict__ pc) {
    int b  = blockIdx.y;
    int ch = blockIdx.x;
    int len = lenp[b];
    int l0 = ch * BROWS;
    if (l0 >= len) return;                       // partial never read downstream
    int wid = threadIdx.x >> 6, lane = threadIdx.x & 63;
    int t = threadIdx.x;
    int lw0 = l0 + wid * WROWS;

    const float* vb = v + (size_t)b * D_;
    float4 v0 = *reinterpret_cast<const float4*>(vb +       lane * 4);
    float4 v1 = *reinterpret_cast<const float4*>(vb + 256 + lane * 4);
    float4 v2 = *reinterpret_cast<const float4*>(vb + 512 + lane * 4);
    float4 v3 = *reinterpret_cast<const float4*>(vb + 768 + lane * 4);
    float cbb = cb[b];

    float m = -INFINITY, s = 0.f;
    float c[16];
    #pragma unroll
    for (int i = 0; i < 16; ++i) c[i] = 0.f;

    __shared__ float e_sm[BROWS];
    __shared__ float lm[4], ls[4];
    __shared__ float lc[4][D_];                  // 16 KB

    if (lw0 < len) {
        #pragma unroll
        for (int r = 0; r < WROWS; ++r) {
            int l = lw0 + r;
            bool valid = l < len;
            const float* row = seq + ((size_t)b * L_ + l) * D_;
            float4 s0 = *reinterpret_cast<const float4*>(row +       lane * 4);
            float4 s1 = *reinterpret_cast<const float4*>(row + 256 + lane * 4);
            float4 s2 = *reinterpret_cast<const float4*>(row + 512 + lane * 4);
            float4 s3 = *reinterpret_cast<const float4*>(row + 768 + lane * 4);
            float acc = 0.f;
            acc = fmaf(s0.x, v0.x, acc); acc = fmaf(s0.y, v0.y, acc);
            acc = fmaf(s0.z, v0.z, acc); acc = fmaf(s0.w, v0.w, acc);
            acc = fmaf(s1.x, v1.x, acc); acc = fmaf(s1.y, v1.y, acc);
            acc = fmaf(s1.z, v1.z, acc); acc = fmaf(s1.w, v1.w, acc);
            acc = fmaf(s2.x, v2.x, acc); acc = fmaf(s2.y, v2.y, acc);
            acc = fmaf(s2.z, v2.z, acc); acc = fmaf(s2.w, v2.w, acc);
            acc = fmaf(s3.x, v3.x, acc); acc = fmaf(s3.y, v3.y, acc);
            acc = fmaf(s3.z, v3.z, acc); acc = fmaf(s3.w, v3.w, acc);
            #pragma unroll
            for (int off = 32; off; off >>= 1) acc += __shfl_xor(acc, off);
            float e = acc + cbb;
            if (lane == 0) e_sm[wid * WROWS + r] = e;
            float mnew  = valid ? fmaxf(m, e) : m;
            float scale = (m == mnew) ? 1.f : __expf(m - mnew);  // handles -inf==-inf
            float p     = valid ? __expf(e - mnew) : 0.f;
            s = s * scale + p;
            c[ 0] = fmaf(p, s0.x, c[ 0] * scale); c[ 1] = fmaf(p, s0.y, c[ 1] * scale);
            c[ 2] = fmaf(p, s0.z, c[ 2] * scale); c[ 3] = fmaf(p, s0.w, c[ 3] * scale);
            c[ 4] = fmaf(p, s1.x, c[ 4] * scale); c[ 5] = fmaf(p, s1.y, c[ 5] * scale);
            c[ 6] = fmaf(p, s1.z, c[ 6] * scale); c[ 7] = fmaf(p, s1.w, c[ 7] * scale);
            c[ 8] = fmaf(p, s2.x, c[ 8] * scale); c[ 9] = fmaf(p, s2.y, c[ 9] * scale);
            c[10] = fmaf(p, s2.z, c[10] * scale); c[11] = fmaf(p, s2.w, c[11] * scale);
            c[12] = fmaf(p, s3.x, c[12] * scale); c[13] = fmaf(p, s3.y, c[13] * scale);
            c[14] = fmaf(p, s3.z, c[14] * scale); c[15] = fmaf(p, s3.w, c[15] * scale);
            m = mnew;
        }
    }

    // stash wave partials in LDS
    {
        float4 w0 = {c[ 0], c[ 1], c[ 2], c[ 3]};
        float4 w1 = {c[ 4], c[ 5], c[ 6], c[ 7]};
        float4 w2 = {c[ 8], c[ 9], c[10], c[11]};
        float4 w3 = {c[12], c[13], c[14], c[15]};
        *reinterpret_cast<float4*>(&lc[wid][      lane * 4]) = w0;
        *reinterpret_cast<float4*>(&lc[wid][256 + lane * 4]) = w1;
        *reinterpret_cast<float4*>(&lc[wid][512 + lane * 4]) = w2;
        *reinterpret_cast<float4*>(&lc[wid][768 + lane * 4]) = w3;
        if (lane == 0) { lm[wid] = m; ls[wid] = s; }
    }
    __syncthreads();

    // coalesced energies write (garbage beyond len is never read)
    if (t < BROWS) energ[(size_t)b * L_ + l0 + t] = e_sm[t];

    // block combine: weights exp(lm[w]-mb); empty waves (lm=-inf) contribute 0
    float mb = fmaxf(fmaxf(lm[0], lm[1]), fmaxf(lm[2], lm[3]));
    float w0 = (lm[0] == mb) ? 1.f : __expf(lm[0] - mb);
    float w1 = (lm[1] == mb) ? 1.f : __expf(lm[1] - mb);
    float w2 = (lm[2] == mb) ? 1.f : __expf(lm[2] - mb);
    float w3 = (lm[3] == mb) ? 1.f : __expf(lm[3] - mb);
    float sb = w0 * ls[0] + w1 * ls[1] + w2 * ls[2] + w3 * ls[3];

    float4 a0 = *reinterpret_cast<const float4*>(&lc[0][t * 4]);
    float4 a1 = *reinterpret_cast<const float4*>(&lc[1][t * 4]);
    float4 a2 = *reinterpret_cast<const float4*>(&lc[2][t * 4]);
    float4 a3 = *reinterpret_cast<const float4*>(&lc[3][t * 4]);
    float4 o;
    o.x = w0 * a0.x + w1 * a1.x + w2 * a2.x + w3 * a3.x;
    o.y = w0 * a0.y + w1 * a1.y + w2 * a2.y + w3 * a3.y;
    o.z = w0 * a0.z + w1 * a1.z + w2 * a2.z + w3 * a3.z;
    o.w = w0 * a0.w + w1 * a1.w + w2 * a2.w + w3 * a3.w;

    size_t pidx = (size_t)b * NCH + ch;
    if (t == 0) { pm[pidx] = mb; ps[pidx] = sb; }
    *reinterpret_cast<float4*>(pc + pidx * D_ + t * 4) = o;
}

// ---- K3: per-b final merge -> contexts + scores ----
__global__ __launch_bounds__(256) void k_final(const float* __restrict__ pm,
                                               const float* __restrict__ ps,
                                               const float* __restrict__ pc,
                                               const float* __restrict__ energ,
                                               const int* __restrict__ lenp,
                                               float* __restrict__ ctx,
                                               float* __restrict__ scores) {
    int b = blockIdx.x, t = threadIdx.x;
    int len = lenp[b];
    int nch = (len + BROWS - 1) / BROWS;         // >= 1
    __shared__ float wgt[NCH];
    __shared__ float Msh, Ssh;
    if (t < 64) {
        float mi = (t < nch) ? pm[(size_t)b * NCH + t] : -INFINITY;
        float si = (t < nch) ? ps[(size_t)b * NCH + t] : 0.f;
        float M = mi;
        #pragma unroll
        for (int off = 32; off; off >>= 1) M = fmaxf(M, __shfl_xor(M, off));
        float ew = (t < nch) ? __expf(mi - M) : 0.f;
        float S  = ew * si;
        #pragma unroll
        for (int off = 32; off; off >>= 1) S += __shfl_xor(S, off);
        if (t < nch) wgt[t] = ew / S;
        if (t == 0) { Msh = M; Ssh = S; }
    }
    __syncthreads();
    float M = Msh;
    float invS = 1.f / Ssh;

    float4 o = {0.f, 0.f, 0.f, 0.f};
    for (int ch = 0; ch < nch; ++ch) {
        float w = wgt[ch];
        float4 p = *reinterpret_cast<const float4*>(pc + ((size_t)b * NCH + ch) * D_ + t * 4);
        o.x = fmaf(w, p.x, o.x); o.y = fmaf(w, p.y, o.y);
        o.z = fmaf(w, p.z, o.z); o.w = fmaf(w, p.w, o.w);
    }
    *reinterpret_cast<float4*>(ctx + (size_t)b * D_ + t * 4) = o;

    #pragma unroll
    for (int i = 0; i < L_ / 256; ++i) {
        int l = i * 256 + t;
        float e = energ[(size_t)b * L_ + l];
        scores[(size_t)b * L_ + l] = (l < len) ? __expf(e - M) * invS : 0.f;
    }
}

extern "C" void kernel_launch(void* const* d_in, const int* in_sizes, int n_in,
                              void* d_out, int out_size, void* d_ws, size_t ws_size,
                              hipStream_t stream) {
    const float* seq     = (const float*)d_in[0];   // [B,L,D]
    const float* query   = (const float*)d_in[1];   // [B,C]
    const int*   lengths = (const int*)  d_in[2];   // [B]
    const float* W_h     = (const float*)d_in[3];   // [C,D]
    const float* b_h     = (const float*)d_in[4];   // [C]

    float* out    = (float*)d_out;
    float* ctx    = out;                 // [B,D]
    float* scores = out + B_ * D_;       // [B,L]

    float* ws    = (float*)d_ws;
    float* v     = ws;                                   // 32768
    float* cb    = ws + 32768;                           // 32
    float* energ = ws + 32800;                           // 65536
    float* vpart = ws + 98336;                           // 524288
    float* pm    = ws + 622624;                          // 2048
    float* ps    = ws + 624672;                          // 2048
    float* pc    = ws + 626720;                          // 2097152

    k_vpart  <<<dim3(CSPLIT, B_), 256, 0, stream>>>(query, W_h, vpart);
    k_vreduce<<<B_, 256, 0, stream>>>(vpart, v, query, b_h, cb);
    k_fused  <<<dim3(NCH, B_), 256, 0, stream>>>(seq, v, cb, lengths, energ, pm, ps, pc);
    k_final  <<<B_, 256, 0, stream>>>(pm, ps, pc, energ, lengths, ctx, scores);
}

// Round 3
// 46.863 us; speedup vs baseline: 1.4731x; 1.0470x over previous
//
#include <hip/hip_runtime.h>
#include <math.h>

#define B_ 32
#define L_ 2048
#define D_ 1024
#define C_ 1024
#define WROWS 8            // rows per wave in fused kernel
#define BROWS 32           // rows per block (4 waves)
#define NCH (L_ / BROWS)   // 64 chunks per batch row

// ws layout (floats):
//   v     : [B_, D_]          off 0
//   cb    : [B_]              off 32768
//   energ : [B_, L_]          off 32800
//   vpart : [16, B_, D_]      off 98336
//   pm    : [B_, NCH]         off 622624
//   ps    : [B_, NCH]         off 624672
//   pc    : [B_, NCH, D_]     off 626720

// ---- K1a: vpart[cc][b][d] = sum_{c in cc-chunk} q[b,c] * W[c,d] ----
// Grid (16 cc, 16 dc). W tile [64c x 64d] read EXACTLY ONCE from HBM.
__global__ __launch_bounds__(256) void k_vpart(const float* __restrict__ q,
                                               const float* __restrict__ W,
                                               float* __restrict__ vpart) {
    int cc = blockIdx.x, dc = blockIdx.y;
    int t  = threadIdx.x;
    __shared__ float qs[B_][65];                 // padded: no bank conflicts
    #pragma unroll
    for (int i = 0; i < 8; ++i) {
        int idx = t + i * 256;                   // 2048 = 32*64
        int b = idx >> 6, cl = idx & 63;
        qs[b][cl] = q[b * C_ + cc * 64 + cl];
    }
    __syncthreads();

    int dl4 = t & 15;                            // float4 slot within 64 d's
    int bg  = t >> 4;                            // 0..15, owns b = 2bg, 2bg+1
    float4 a0 = {0,0,0,0}, a1 = {0,0,0,0};
    const float4* W4 = reinterpret_cast<const float4*>(W);
    for (int c = 0; c < 64; ++c) {
        float4 w = W4[(size_t)(cc * 64 + c) * (D_ / 4) + dc * 16 + dl4];
        float q0 = qs[bg * 2 + 0][c];
        float q1 = qs[bg * 2 + 1][c];
        a0.x = fmaf(q0, w.x, a0.x); a0.y = fmaf(q0, w.y, a0.y);
        a0.z = fmaf(q0, w.z, a0.z); a0.w = fmaf(q0, w.w, a0.w);
        a1.x = fmaf(q1, w.x, a1.x); a1.y = fmaf(q1, w.y, a1.y);
        a1.z = fmaf(q1, w.z, a1.z); a1.w = fmaf(q1, w.w, a1.w);
    }
    size_t base = ((size_t)cc * B_ + bg * 2) * D_ + dc * 64 + dl4 * 4;
    *reinterpret_cast<float4*>(vpart + base)       = a0;
    *reinterpret_cast<float4*>(vpart + base + D_)  = a1;
}

// ---- K1b: reduce vpart -> v;  cb[b] = dot(b_h, query[b]) ----
__global__ __launch_bounds__(256) void k_vreduce(const float* __restrict__ vpart,
                                                 float* __restrict__ v,
                                                 const float* __restrict__ q,
                                                 const float* __restrict__ bh,
                                                 float* __restrict__ cb) {
    int b = blockIdx.x, dq = blockIdx.y, t = threadIdx.x;
    int d = dq * 256 + t;
    float a = 0.f;
    #pragma unroll
    for (int cc = 0; cc < 16; ++cc)
        a += vpart[((size_t)cc * B_ + b) * D_ + d];
    v[(size_t)b * D_ + d] = a;

    if (dq == 0) {
        float s = 0.f;
        for (int c = t; c < C_; c += 256) s += bh[c] * q[b * C_ + c];
        __shared__ float red[256];
        red[t] = s; __syncthreads();
        for (int off = 128; off > 0; off >>= 1) {
            if (t < off) red[t] += red[t + off];
            __syncthreads();
        }
        if (t == 0) cb[b] = red[0];
    }
}

// ---- K2 fused: energies + online-softmax context partials, ONE seq pass ----
__global__ __launch_bounds__(256) void k_fused(const float* __restrict__ seq,
                                               const float* __restrict__ v,
                                               const float* __restrict__ cb,
                                               const int* __restrict__ lenp,
                                               float* __restrict__ energ,
                                               float* __restrict__ pm,
                                               float* __restrict__ ps,
                                               float* __restrict__ pc) {
    int b  = blockIdx.y;
    int ch = blockIdx.x;
    int len = lenp[b];
    int l0 = ch * BROWS;
    if (l0 >= len) return;                       // partial never read downstream
    int wid = threadIdx.x >> 6, lane = threadIdx.x & 63;
    int t = threadIdx.x;
    int lw0 = l0 + wid * WROWS;

    const float* vb = v + (size_t)b * D_;
    float4 v0 = *reinterpret_cast<const float4*>(vb +       lane * 4);
    float4 v1 = *reinterpret_cast<const float4*>(vb + 256 + lane * 4);
    float4 v2 = *reinterpret_cast<const float4*>(vb + 512 + lane * 4);
    float4 v3 = *reinterpret_cast<const float4*>(vb + 768 + lane * 4);
    float cbb = cb[b];

    float m = -INFINITY, s = 0.f;
    float c[16];
    #pragma unroll
    for (int i = 0; i < 16; ++i) c[i] = 0.f;

    __shared__ float e_sm[BROWS];
    __shared__ float lm[4], ls[4];
    __shared__ float lc[4][D_];                  // 16 KB

    if (lw0 < len) {
        #pragma unroll
        for (int r = 0; r < WROWS; ++r) {
            int l = lw0 + r;
            bool valid = l < len;
            const float* row = seq + ((size_t)b * L_ + l) * D_;
            float4 s0 = *reinterpret_cast<const float4*>(row +       lane * 4);
            float4 s1 = *reinterpret_cast<const float4*>(row + 256 + lane * 4);
            float4 s2 = *reinterpret_cast<const float4*>(row + 512 + lane * 4);
            float4 s3 = *reinterpret_cast<const float4*>(row + 768 + lane * 4);
            float acc = 0.f;
            acc = fmaf(s0.x, v0.x, acc); acc = fmaf(s0.y, v0.y, acc);
            acc = fmaf(s0.z, v0.z, acc); acc = fmaf(s0.w, v0.w, acc);
            acc = fmaf(s1.x, v1.x, acc); acc = fmaf(s1.y, v1.y, acc);
            acc = fmaf(s1.z, v1.z, acc); acc = fmaf(s1.w, v1.w, acc);
            acc = fmaf(s2.x, v2.x, acc); acc = fmaf(s2.y, v2.y, acc);
            acc = fmaf(s2.z, v2.z, acc); acc = fmaf(s2.w, v2.w, acc);
            acc = fmaf(s3.x, v3.x, acc); acc = fmaf(s3.y, v3.y, acc);
            acc = fmaf(s3.z, v3.z, acc); acc = fmaf(s3.w, v3.w, acc);
            #pragma unroll
            for (int off = 32; off; off >>= 1) acc += __shfl_xor(acc, off);
            float e = acc + cbb;
            if (lane == 0) e_sm[wid * WROWS + r] = e;
            float mnew  = valid ? fmaxf(m, e) : m;
            float scale = (m == mnew) ? 1.f : __expf(m - mnew);  // handles -inf==-inf
            float p     = valid ? __expf(e - mnew) : 0.f;
            s = s * scale + p;
            c[ 0] = fmaf(p, s0.x, c[ 0] * scale); c[ 1] = fmaf(p, s0.y, c[ 1] * scale);
            c[ 2] = fmaf(p, s0.z, c[ 2] * scale); c[ 3] = fmaf(p, s0.w, c[ 3] * scale);
            c[ 4] = fmaf(p, s1.x, c[ 4] * scale); c[ 5] = fmaf(p, s1.y, c[ 5] * scale);
            c[ 6] = fmaf(p, s1.z, c[ 6] * scale); c[ 7] = fmaf(p, s1.w, c[ 7] * scale);
            c[ 8] = fmaf(p, s2.x, c[ 8] * scale); c[ 9] = fmaf(p, s2.y, c[ 9] * scale);
            c[10] = fmaf(p, s2.z, c[10] * scale); c[11] = fmaf(p, s2.w, c[11] * scale);
            c[12] = fmaf(p, s3.x, c[12] * scale); c[13] = fmaf(p, s3.y, c[13] * scale);
            c[14] = fmaf(p, s3.z, c[14] * scale); c[15] = fmaf(p, s3.w, c[15] * scale);
            m = mnew;
        }
    }

    {
        float4 w0 = {c[ 0], c[ 1], c[ 2], c[ 3]};
        float4 w1 = {c[ 4], c[ 5], c[ 6], c[ 7]};
        float4 w2 = {c[ 8], c[ 9], c[10], c[11]};
        float4 w3 = {c[12], c[13], c[14], c[15]};
        *reinterpret_cast<float4*>(&lc[wid][      lane * 4]) = w0;
        *reinterpret_cast<float4*>(&lc[wid][256 + lane * 4]) = w1;
        *reinterpret_cast<float4*>(&lc[wid][512 + lane * 4]) = w2;
        *reinterpret_cast<float4*>(&lc[wid][768 + lane * 4]) = w3;
        if (lane == 0) { lm[wid] = m; ls[wid] = s; }
    }
    __syncthreads();

    if (t < BROWS) energ[(size_t)b * L_ + l0 + t] = e_sm[t];

    float mb = fmaxf(fmaxf(lm[0], lm[1]), fmaxf(lm[2], lm[3]));
    float w0 = (lm[0] == mb) ? 1.f : __expf(lm[0] - mb);
    float w1 = (lm[1] == mb) ? 1.f : __expf(lm[1] - mb);
    float w2 = (lm[2] == mb) ? 1.f : __expf(lm[2] - mb);
    float w3 = (lm[3] == mb) ? 1.f : __expf(lm[3] - mb);
    float sb = w0 * ls[0] + w1 * ls[1] + w2 * ls[2] + w3 * ls[3];

    float4 a0 = *reinterpret_cast<const float4*>(&lc[0][t * 4]);
    float4 a1 = *reinterpret_cast<const float4*>(&lc[1][t * 4]);
    float4 a2 = *reinterpret_cast<const float4*>(&lc[2][t * 4]);
    float4 a3 = *reinterpret_cast<const float4*>(&lc[3][t * 4]);
    float4 o;
    o.x = w0 * a0.x + w1 * a1.x + w2 * a2.x + w3 * a3.x;
    o.y = w0 * a0.y + w1 * a1.y + w2 * a2.y + w3 * a3.y;
    o.z = w0 * a0.z + w1 * a1.z + w2 * a2.z + w3 * a3.z;
    o.w = w0 * a0.w + w1 * a1.w + w2 * a2.w + w3 * a3.w;

    size_t pidx = (size_t)b * NCH + ch;
    if (t == 0) { pm[pidx] = mb; ps[pidx] = sb; }
    *reinterpret_cast<float4*>(pc + pidx * D_ + t * 4) = o;
}

// ---- K3: per-(b, slice) final merge -> contexts + scores. 256 blocks. ----
__global__ __launch_bounds__(256) void k_final(const float* __restrict__ pm,
                                               const float* __restrict__ ps,
                                               const float* __restrict__ pc,
                                               const float* __restrict__ energ,
                                               const int* __restrict__ lenp,
                                               float* __restrict__ ctx,
                                               float* __restrict__ scores) {
    int b = blockIdx.x, sl = blockIdx.y, t = threadIdx.x;
    int len = lenp[b];
    int nch = (len + BROWS - 1) / BROWS;         // 1..64
    __shared__ float wgt[NCH];
    __shared__ float Msh, Ssh;
    if (t < 64) {
        float mi = (t < nch) ? pm[(size_t)b * NCH + t] : -INFINITY;
        float si = (t < nch) ? ps[(size_t)b * NCH + t] : 0.f;
        float M = mi;
        #pragma unroll
        for (int off = 32; off; off >>= 1) M = fmaxf(M, __shfl_xor(M, off));
        float ew = (t < nch) ? __expf(mi - M) : 0.f;
        float S  = ew * si;
        #pragma unroll
        for (int off = 32; off; off >>= 1) S += __shfl_xor(S, off);
        if (t < nch) wgt[t] = ew / S;
        if (t == 0) { Msh = M; Ssh = S; }
    }
    __syncthreads();
    float M = Msh;
    float invS = 1.f / Ssh;

    if (t < 128) {                               // context slice: 128 d's
        int d = sl * 128 + t;
        float o = 0.f;
        for (int ch = 0; ch < nch; ++ch)
            o = fmaf(wgt[ch], pc[((size_t)b * NCH + ch) * D_ + d], o);
        ctx[(size_t)b * D_ + d] = o;
    }

    int l = sl * 256 + t;                        // scores slice: 256 l's
    float e = energ[(size_t)b * L_ + l];
    scores[(size_t)b * L_ + l] = (l < len) ? __expf(e - M) * invS : 0.f;
}

extern "C" void kernel_launch(void* const* d_in, const int* in_sizes, int n_in,
                              void* d_out, int out_size, void* d_ws, size_t ws_size,
                              hipStream_t stream) {
    const float* seq     = (const float*)d_in[0];   // [B,L,D]
    const float* query   = (const float*)d_in[1];   // [B,C]
    const int*   lengths = (const int*)  d_in[2];   // [B]
    const float* W_h     = (const float*)d_in[3];   // [C,D]
    const float* b_h     = (const float*)d_in[4];   // [C]

    float* out    = (float*)d_out;
    float* ctx    = out;                 // [B,D]
    float* scores = out + B_ * D_;       // [B,L]

    float* ws    = (float*)d_ws;
    float* v     = ws;                                   // 32768
    float* cb    = ws + 32768;                           // 32
    float* energ = ws + 32800;                           // 65536
    float* vpart = ws + 98336;                           // 524288
    float* pm    = ws + 622624;                          // 2048
    float* ps    = ws + 624672;                          // 2048
    float* pc    = ws + 626720;                          // 2097152

    k_vpart  <<<dim3(16, 16), 256, 0, stream>>>(query, W_h, vpart);
    k_vreduce<<<dim3(B_, 4), 256, 0, stream>>>(vpart, v, query, b_h, cb);
    k_fused  <<<dim3(NCH, B_), 256, 0, stream>>>(seq, v, cb, lengths, energ, pm, ps, pc);
    k_final  <<<dim3(B_, 8), 256, 0, stream>>>(pm, ps, pc, energ, lengths, ctx, scores);
}